// Round 1
// baseline (658.170 us; speedup 1.0000x reference)
//
#include <hip/hip_runtime.h>

#define IN1 16
#define HIDC 10
#define OUT3 16
#define MAXB 32

// ---------------- zero workspace ----------------
__global__ __launch_bounds__(256) void zero_kernel(float* __restrict__ p, int n) {
  int i = blockIdx.x * blockDim.x + threadIdx.x;
  int stride = gridDim.x * blockDim.x;
  for (; i < n; i += stride) p[i] = 0.f;
}

// ---------------- pack edge-NN params: pa[k]={wh0,wh1,wg0,wg1}, pb[k]={bh,bg} ----
__global__ __launch_bounds__(256) void pack_all_kernel(
    const float* __restrict__ wh1, const float* __restrict__ bh1,
    const float* __restrict__ wg1, const float* __restrict__ bg1,
    const float* __restrict__ wh2, const float* __restrict__ bh2,
    const float* __restrict__ wg2, const float* __restrict__ bg2,
    const float* __restrict__ wh3, const float* __restrict__ bh3,
    const float* __restrict__ wg3, const float* __restrict__ bg3,
    float4* __restrict__ pa1, float2* __restrict__ pb1,
    float4* __restrict__ pa2, float2* __restrict__ pb2,
    float4* __restrict__ pa3, float2* __restrict__ pb3)
{
  const int D1 = IN1 * HIDC, D2 = HIDC * HIDC, D3 = HIDC * OUT3;
  int k = threadIdx.x;
  if (k < D1) {
    pa1[k] = make_float4(wh1[k], wh1[D1 + k], wg1[k], wg1[D1 + k]);
    pb1[k] = make_float2(bh1[k], bg1[k]);
  }
  if (k < D2) {
    pa2[k] = make_float4(wh2[k], wh2[D2 + k], wg2[k], wg2[D2 + k]);
    pb2[k] = make_float2(bh2[k], bg2[k]);
  }
  if (k < D3) {
    pa3[k] = make_float4(wh3[k], wh3[D3 + k], wg3[k], wg3[D3 + k]);
    pb3[k] = make_float2(bh3[k], bg3[k]);
  }
}

// ---------------- edge kernel: 2 edges per thread ----------------
// w[e,k] = relu(emb[t[e],k] * (f0*wh0[k]+f1*wh1[k]+bh[k]) + (f0*wg0[k]+f1*wg1[k]+bg[k]))
// acc[e,o] = sum_i x[src[e],i] * w[e, i*OUT_C+o];  atomicAdd into agg[dst[e]].
template<int IN_C, int OUT_C, bool COUNT>
__global__ __launch_bounds__(256) void edge_kernel(
    const float* __restrict__ xin,          // [N, IN_C]
    const float4* __restrict__ ef4,         // [ceil(E/2)] : {f0_e0,f1_e0,f0_e1,f1_e1}
    const int* __restrict__ et,
    const int* __restrict__ esrc,
    const int* __restrict__ edst,
    const float* __restrict__ emb,          // [25, D]
    const float4* __restrict__ pa,          // [D]
    const float2* __restrict__ pb,          // [D]
    float* __restrict__ agg,                // [N, OUT_C] (atomic)
    float* __restrict__ cnt,                // [N] (atomic, only if COUNT)
    int E)
{
  constexpr int D = IN_C * OUT_C;
  int gid = blockIdx.x * blockDim.x + threadIdx.x;
  int e0 = 2 * gid;
  if (e0 >= E) return;
  int e1 = e0 + 1;
  bool has1 = (e1 < E);

  float4 f = ef4[gid];
  int t0 = et[e0], s0 = esrc[e0], d0 = edst[e0];
  int t1 = has1 ? et[e1] : t0;
  int s1 = has1 ? esrc[e1] : s0;
  int d1 = has1 ? edst[e1] : d0;

  const float* __restrict__ er0 = emb + (size_t)t0 * D;
  const float* __restrict__ er1 = emb + (size_t)t1 * D;

  float xs0[IN_C], xs1[IN_C];
  #pragma unroll
  for (int i = 0; i < IN_C; i++) xs0[i] = xin[(size_t)s0 * IN_C + i];
  #pragma unroll
  for (int i = 0; i < IN_C; i++) xs1[i] = xin[(size_t)s1 * IN_C + i];

  float acc0[OUT_C], acc1[OUT_C];
  #pragma unroll
  for (int o = 0; o < OUT_C; o++) { acc0[o] = 0.f; acc1[o] = 0.f; }

  for (int i = 0; i < IN_C; i++) {
    float x0 = xs0[i], x1 = xs1[i];
    #pragma unroll
    for (int o = 0; o < OUT_C; o++) {
      int k = i * OUT_C + o;
      float4 a = pa[k];
      float2 b = pb[k];
      float h0 = fmaf(f.x, a.x, fmaf(f.y, a.y, b.x));
      float g0 = fmaf(f.x, a.z, fmaf(f.y, a.w, b.y));
      float h1 = fmaf(f.z, a.x, fmaf(f.w, a.y, b.x));
      float g1 = fmaf(f.z, a.z, fmaf(f.w, a.w, b.y));
      float w0 = fmaxf(fmaf(er0[k], h0, g0), 0.f);
      float w1 = fmaxf(fmaf(er1[k], h1, g1), 0.f);
      acc0[o] = fmaf(x0, w0, acc0[o]);
      acc1[o] = fmaf(x1, w1, acc1[o]);
    }
  }

  float* r0 = agg + (size_t)d0 * OUT_C;
  #pragma unroll
  for (int o = 0; o < OUT_C; o++) atomicAdd(&r0[o], acc0[o]);
  if (has1) {
    float* r1 = agg + (size_t)d1 * OUT_C;
    #pragma unroll
    for (int o = 0; o < OUT_C; o++) atomicAdd(&r1[o], acc1[o]);
  }
  if (COUNT) {
    atomicAdd(&cnt[d0], 1.0f);
    if (has1) atomicAdd(&cnt[d1], 1.0f);
  }
}

// ---------------- node update: h = relu(agg/max(cnt,1) + x@root + bias), in-place on agg ----
template<int IN_C, int OUT_C>
__global__ __launch_bounds__(256) void node_kernel(
    const float* __restrict__ xin,   // [N, IN_C]
    const float* __restrict__ cnt,   // [N]
    const float* __restrict__ root,  // [IN_C, OUT_C]
    const float* __restrict__ bias,  // [OUT_C]
    float* __restrict__ h,           // [N, OUT_C]: in = agg sums, out = activated
    int N)
{
  int n = blockIdx.x * blockDim.x + threadIdx.x;
  if (n >= N) return;
  float inv = 1.0f / fmaxf(cnt[n], 1.0f);
  float xs[IN_C];
  #pragma unroll
  for (int i = 0; i < IN_C; i++) xs[i] = xin[(size_t)n * IN_C + i];
  #pragma unroll
  for (int o = 0; o < OUT_C; o++) {
    float v = fmaf(h[(size_t)n * OUT_C + o], inv, bias[o]);
    #pragma unroll
    for (int i = 0; i < IN_C; i++) v = fmaf(xs[i], root[i * OUT_C + o], v);
    h[(size_t)n * OUT_C + o] = fmaxf(v, 0.f);
  }
}

// ---------------- layer-3 node update fused with gated pooling ----------------
__global__ __launch_bounds__(256) void node3_pool_kernel(
    const float* __restrict__ xin,   // h2 [N, HIDC]
    const float* __restrict__ agg,   // [N, OUT3]
    const float* __restrict__ cnt,   // [N]
    const float* __restrict__ root,  // [HIDC, OUT3]
    const float* __restrict__ bias,  // [OUT3]
    const int* __restrict__ ctype,
    const int* __restrict__ bids,
    float* __restrict__ psum,        // [B, OUT3] (atomic)
    float* __restrict__ pcnt,        // [B] (atomic)
    int N, int B)
{
  __shared__ float ssum[MAXB * OUT3];
  __shared__ float scnt[MAXB];
  int tid = threadIdx.x;
  for (int i = tid; i < B * OUT3; i += blockDim.x) ssum[i] = 0.f;
  for (int i = tid; i < B; i += blockDim.x) scnt[i] = 0.f;
  __syncthreads();

  int n = blockIdx.x * blockDim.x + tid;
  if (n < N && ctype[n] == 1) {
    int b = bids[n];
    float inv = 1.0f / fmaxf(cnt[n], 1.0f);
    float xs[HIDC];
    #pragma unroll
    for (int i = 0; i < HIDC; i++) xs[i] = xin[(size_t)n * HIDC + i];
    #pragma unroll
    for (int o = 0; o < OUT3; o++) {
      float v = fmaf(agg[(size_t)n * OUT3 + o], inv, bias[o]);
      #pragma unroll
      for (int i = 0; i < HIDC; i++) v = fmaf(xs[i], root[i * OUT3 + o], v);
      v = fmaxf(v, 0.f);
      atomicAdd(&ssum[b * OUT3 + o], v);
    }
    atomicAdd(&scnt[b], 1.0f);
  }
  __syncthreads();
  for (int i = tid; i < B * OUT3; i += blockDim.x) atomicAdd(&psum[i], ssum[i]);
  for (int i = tid; i < B; i += blockDim.x) atomicAdd(&pcnt[i], scnt[i]);
}

__global__ __launch_bounds__(128) void finalize_kernel(
    const float* __restrict__ psum, const float* __restrict__ pcnt,
    float* __restrict__ out, int B)
{
  int i = blockIdx.x * blockDim.x + threadIdx.x;
  if (i >= B * OUT3) return;
  int b = i / OUT3;
  out[i] = psum[i] / fmaxf(pcnt[b], 1.0f);
}

// ---------------- launch ----------------
extern "C" void kernel_launch(void* const* d_in, const int* in_sizes, int n_in,
                              void* d_out, int out_size, void* d_ws, size_t ws_size,
                              hipStream_t stream)
{
  const float* x     = (const float*)d_in[0];
  const float* ef    = (const float*)d_in[1];
  const int*   et    = (const int*)d_in[2];
  const int*   esrc  = (const int*)d_in[3];
  const int*   edst  = (const int*)d_in[4];
  const int*   ctype = (const int*)d_in[5];
  const int*   bids  = (const int*)d_in[6];
  // d_in[7] = batch_size (device scalar; B derived from out_size instead)
  const float* emb1 = (const float*)d_in[8];
  const float* wh1  = (const float*)d_in[9];
  const float* bh1  = (const float*)d_in[10];
  const float* wg1  = (const float*)d_in[11];
  const float* bg1  = (const float*)d_in[12];
  const float* root1= (const float*)d_in[13];
  const float* bias1= (const float*)d_in[14];
  const float* emb2 = (const float*)d_in[15];
  const float* wh2  = (const float*)d_in[16];
  const float* bh2  = (const float*)d_in[17];
  const float* wg2  = (const float*)d_in[18];
  const float* bg2  = (const float*)d_in[19];
  const float* root2= (const float*)d_in[20];
  const float* bias2= (const float*)d_in[21];
  const float* emb3 = (const float*)d_in[22];
  const float* wh3  = (const float*)d_in[23];
  const float* bh3  = (const float*)d_in[24];
  const float* wg3  = (const float*)d_in[25];
  const float* bg3  = (const float*)d_in[26];
  const float* root3= (const float*)d_in[27];
  const float* bias3= (const float*)d_in[28];

  const int N = in_sizes[0] / IN1;
  const int E = in_sizes[2];
  const int B = out_size / OUT3;

  // workspace layout (floats); all section sizes are multiples of 4 -> 16B aligned
  float* ws   = (float*)d_ws;
  float* agg1 = ws;                                // N*HIDC
  float* agg2 = agg1 + (size_t)N * HIDC;           // N*HIDC
  float* agg3 = agg2 + (size_t)N * HIDC;           // N*OUT3
  float* cnt  = agg3 + (size_t)N * OUT3;           // N
  float* psum = cnt + N;                           // B*OUT3
  float* pcnt = psum + (size_t)B * OUT3;           // B  (B=8 -> stays 16B aligned)
  float* pk   = pcnt + B;
  float4* pa1 = (float4*)pk;                       // 160*4
  float2* pb1 = (float2*)(pk + 640);               // 160*2
  float4* pa2 = (float4*)(pk + 960);               // 100*4
  float2* pb2 = (float2*)(pk + 1360);              // 100*2
  float4* pa3 = (float4*)(pk + 1560);              // 160*4
  float2* pb3 = (float2*)(pk + 2200);              // 160*2

  const int zeroN = (int)((size_t)N * (HIDC + HIDC + OUT3 + 1) + (size_t)B * (OUT3 + 1));
  zero_kernel<<<512, 256, 0, stream>>>(ws, zeroN);
  pack_all_kernel<<<1, 256, 0, stream>>>(wh1, bh1, wg1, bg1, wh2, bh2, wg2, bg2,
                                         wh3, bh3, wg3, bg3,
                                         pa1, pb1, pa2, pb2, pa3, pb3);

  const int epairs = (E + 1) / 2;
  dim3 eg((epairs + 255) / 256), eb(256);
  dim3 ng((N + 255) / 256), nb(256);

  edge_kernel<IN1, HIDC, true><<<eg, eb, 0, stream>>>(
      x, (const float4*)ef, et, esrc, edst, emb1, pa1, pb1, agg1, cnt, E);
  node_kernel<IN1, HIDC><<<ng, nb, 0, stream>>>(x, cnt, root1, bias1, agg1, N);

  edge_kernel<HIDC, HIDC, false><<<eg, eb, 0, stream>>>(
      agg1, (const float4*)ef, et, esrc, edst, emb2, pa2, pb2, agg2, nullptr, E);
  node_kernel<HIDC, HIDC><<<ng, nb, 0, stream>>>(agg1, cnt, root2, bias2, agg2, N);

  edge_kernel<HIDC, OUT3, false><<<eg, eb, 0, stream>>>(
      agg2, (const float4*)ef, et, esrc, edst, emb3, pa3, pb3, agg3, nullptr, E);
  node3_pool_kernel<<<ng, nb, 0, stream>>>(agg2, agg3, cnt, root3, bias3,
                                           ctype, bids, psum, pcnt, N, B);

  finalize_kernel<<<1, 128, 0, stream>>>(psum, pcnt, (float*)d_out, B);
}

// Round 2
// 281.108 us; speedup vs baseline: 2.3413x; 2.3413x over previous
//
#include <hip/hip_runtime.h>

#define IN1 16
#define HIDC 10
#define OUT3 16
#define NTYPES 25
#define MAXB 32

// ---------------- zero two int regions ----------------
__global__ __launch_bounds__(256) void zero2_kernel(int* __restrict__ a, int na,
                                                    int* __restrict__ b, int nb) {
  int i = blockIdx.x * blockDim.x + threadIdx.x;
  int s = gridDim.x * blockDim.x;
  for (int j = i; j < na; j += s) a[j] = 0;
  for (int j = i; j < nb; j += s) b[j] = 0;
}

// ---------------- histogram + within-bucket rank (1 atomic per edge) ----------
__global__ __launch_bounds__(256) void hist_kernel(const int* __restrict__ edst,
                                                   int* __restrict__ deg,
                                                   int* __restrict__ pos, int E) {
  int e = blockIdx.x * blockDim.x + threadIdx.x;
  if (e < E) pos[e] = atomicAdd(&deg[edst[e]], 1);
}

// ---------------- single-block exclusive scan (int4 vectorized) ----------------
__global__ __launch_bounds__(1024) void scan_kernel(const int4* __restrict__ deg4,
                                                    int* __restrict__ row_ptr, int N) {
  __shared__ int wsums[16];
  __shared__ int s_run;
  int tid = threadIdx.x, lane = tid & 63, wid = tid >> 6;
  if (tid == 0) s_run = 0;
  __syncthreads();
  int N4 = (N + 3) >> 2;
  for (int base = 0; base < N4; base += 1024) {
    int i4 = base + tid;
    int4 v = make_int4(0, 0, 0, 0);
    if (i4 < N4) v = deg4[i4];
    int idx0 = i4 * 4;
    if (idx0 + 1 >= N) v.y = 0;
    if (idx0 + 2 >= N) v.z = 0;
    if (idx0 + 3 >= N) v.w = 0;
    int s = v.x + v.y + v.z + v.w;
    int x = s;
    #pragma unroll
    for (int off = 1; off < 64; off <<= 1) {
      int y = __shfl_up(x, off);
      if (lane >= off) x += y;
    }
    if (lane == 63) wsums[wid] = x;
    __syncthreads();
    if (tid < 16) {
      int w = wsums[tid];
      #pragma unroll
      for (int off = 1; off < 16; off <<= 1) {
        int y = __shfl_up(w, off);
        if (tid >= off) w += y;
      }
      wsums[tid] = w;
    }
    __syncthreads();
    int excl = x - s + ((wid > 0) ? wsums[wid - 1] : 0) + s_run;
    int total = wsums[15];
    if (idx0 < N) row_ptr[idx0] = excl;
    if (idx0 + 1 < N) row_ptr[idx0 + 1] = excl + v.x;
    if (idx0 + 2 < N) row_ptr[idx0 + 2] = excl + v.x + v.y;
    if (idx0 + 3 < N) row_ptr[idx0 + 3] = excl + v.x + v.y + v.z;
    __syncthreads();
    if (tid == 0) s_run += total;
    __syncthreads();
  }
  if (threadIdx.x == 0) row_ptr[N] = s_run;
}

// ---------------- scatter edges into CSR order (plain stores) ----------------
__global__ __launch_bounds__(256) void permute_kernel(
    const int* __restrict__ edst, const int* __restrict__ esrc,
    const int* __restrict__ et, const float2* __restrict__ ef,
    const int* __restrict__ row_ptr, const int* __restrict__ pos,
    int4* __restrict__ edges, int E) {
  int e = blockIdx.x * blockDim.x + threadIdx.x;
  if (e >= E) return;
  int d = edst[e];
  int idx = row_ptr[d] + pos[e];
  float2 f = ef[e];
  int4 r;
  r.x = esrc[e];
  r.y = et[e];
  r.z = __float_as_int(f.x);
  r.w = __float_as_int(f.y);
  edges[idx] = r;
}

// ---------------- fused gather layer: msg-agg + mean + root + bias + relu -----
// lane = (node_local, o16) with o16 in [0,16); 16 lanes per node.
template<int IN_C, int O, bool POOL, int BS>
__global__ __launch_bounds__(BS) void layer_kernel(
    const float* __restrict__ xin,      // [N, IN_C]
    const int4* __restrict__ edges,     // CSR by dst: {src, type, f0, f1}
    const int* __restrict__ row_ptr,    // [N+1]
    const float* __restrict__ emb,      // [25, D]
    const float* __restrict__ wh, const float* __restrict__ bh,
    const float* __restrict__ wg, const float* __restrict__ bg,
    const float* __restrict__ root,     // [IN_C, O]
    const float* __restrict__ bias,     // [O]
    float* __restrict__ hout,           // [N, O], or psum[B*16] if POOL
    const int* __restrict__ ctype, const int* __restrict__ bids,
    float* __restrict__ pcnt,           // [B] (POOL only)
    int N, int B)
{
  constexpr int D = IN_C * O;
  constexpr int ESTR = D + 8;           // padded LDS row stride for emb
  constexpr int NPB = BS / 16;          // nodes per block
  __shared__ float4 s_pa[D];            // {wh0,wh1,wg0,wg1}
  __shared__ float2 s_pb[D];            // {bh,bg}
  __shared__ float s_emb[NTYPES * ESTR];
  __shared__ float s_root[D];
  __shared__ float s_bias[O];
  __shared__ float s_psum[POOL ? (MAXB * 16) : 1];
  __shared__ float s_pcnt[POOL ? MAXB : 1];

  int tid = threadIdx.x;
  for (int k = tid; k < D; k += BS) {
    s_pa[k] = make_float4(wh[k], wh[D + k], wg[k], wg[D + k]);
    s_pb[k] = make_float2(bh[k], bg[k]);
    s_root[k] = root[k];
  }
  for (int k = tid; k < NTYPES * D; k += BS) {
    int t = k / D, j = k - t * D;
    s_emb[t * ESTR + j] = emb[k];
  }
  if (tid < O) s_bias[tid] = bias[tid];
  if (POOL) {
    for (int i = tid; i < MAXB * 16; i += BS) s_psum[i] = 0.f;
    for (int i = tid; i < MAXB; i += BS) s_pcnt[i] = 0.f;
  }
  __syncthreads();

  int nl = tid >> 4;
  int o = tid & 15;
  int oc = (O == 16) ? o : ((o < O) ? o : 0);   // clamp idle lanes
  int n = blockIdx.x * NPB + nl;

  float acc = 0.f;
  int start = 0, end = 0;
  if (n < N) { start = row_ptr[n]; end = row_ptr[n + 1]; }
  for (int e = start; e < end; ++e) {
    int4 r = edges[e];
    int src = r.x, t = r.y;
    float f0 = __int_as_float(r.z), f1 = __int_as_float(r.w);
    const float* __restrict__ xr = xin + (size_t)src * IN_C;
    const float* __restrict__ er = s_emb + t * ESTR;
    #pragma unroll
    for (int i = 0; i < IN_C; ++i) {
      int k = i * O + oc;
      float4 a = s_pa[k];
      float2 b = s_pb[k];
      float h = fmaf(f0, a.x, fmaf(f1, a.y, b.x));
      float g = fmaf(f0, a.z, fmaf(f1, a.w, b.y));
      float w = fmaxf(fmaf(er[k], h, g), 0.f);
      acc = fmaf(xr[i], w, acc);
    }
  }

  if (n < N && o < O) {
    float inv = 1.0f / fmaxf((float)(end - start), 1.0f);
    float v = fmaf(acc, inv, s_bias[o]);
    const float* __restrict__ xr = xin + (size_t)n * IN_C;
    #pragma unroll
    for (int i = 0; i < IN_C; ++i) v = fmaf(xr[i], s_root[i * O + o], v);
    v = fmaxf(v, 0.f);
    if (!POOL) {
      hout[(size_t)n * O + o] = v;
    } else {
      if (ctype[n] == 1) {
        int b = bids[n];
        atomicAdd(&s_psum[b * 16 + o], v);
        if (o == 0) atomicAdd(&s_pcnt[b], 1.0f);
      }
    }
  }

  if (POOL) {
    __syncthreads();
    for (int i = tid; i < B * 16; i += BS) {
      float v = s_psum[i];
      if (v != 0.f) atomicAdd(&hout[i], v);    // hout = psum (global)
    }
    for (int i = tid; i < B; i += BS) {
      float c = s_pcnt[i];
      if (c != 0.f) atomicAdd(&pcnt[i], c);
    }
  }
}

__global__ __launch_bounds__(256) void finalize_kernel(
    const float* __restrict__ psum, const float* __restrict__ pcnt,
    float* __restrict__ out, int B) {
  int i = blockIdx.x * blockDim.x + threadIdx.x;
  if (i >= B * OUT3) return;
  int b = i / OUT3;
  out[i] = psum[i] / fmaxf(pcnt[b], 1.0f);
}

// ---------------- launch ----------------
extern "C" void kernel_launch(void* const* d_in, const int* in_sizes, int n_in,
                              void* d_out, int out_size, void* d_ws, size_t ws_size,
                              hipStream_t stream)
{
  const float* x     = (const float*)d_in[0];
  const float* ef    = (const float*)d_in[1];
  const int*   et    = (const int*)d_in[2];
  const int*   esrc  = (const int*)d_in[3];
  const int*   edst  = (const int*)d_in[4];
  const int*   ctype = (const int*)d_in[5];
  const int*   bids  = (const int*)d_in[6];
  const float* emb1 = (const float*)d_in[8];
  const float* wh1  = (const float*)d_in[9];
  const float* bh1  = (const float*)d_in[10];
  const float* wg1  = (const float*)d_in[11];
  const float* bg1  = (const float*)d_in[12];
  const float* root1= (const float*)d_in[13];
  const float* bias1= (const float*)d_in[14];
  const float* emb2 = (const float*)d_in[15];
  const float* wh2  = (const float*)d_in[16];
  const float* bh2  = (const float*)d_in[17];
  const float* wg2  = (const float*)d_in[18];
  const float* bg2  = (const float*)d_in[19];
  const float* root2= (const float*)d_in[20];
  const float* bias2= (const float*)d_in[21];
  const float* emb3 = (const float*)d_in[22];
  const float* wh3  = (const float*)d_in[23];
  const float* bh3  = (const float*)d_in[24];
  const float* wg3  = (const float*)d_in[25];
  const float* bg3  = (const float*)d_in[26];
  const float* root3= (const float*)d_in[27];
  const float* bias3= (const float*)d_in[28];

  const int N = in_sizes[0] / IN1;
  const int E = in_sizes[2];
  const int B = out_size / OUT3;

  // workspace layout (16B-aligned sections)
  int4* edges   = (int4*)d_ws;                       // E recs (16B each)
  int*  deg     = (int*)(edges + E);                 // N
  int*  pos     = deg + N;                           // E
  int*  row_ptr = pos + E;                           // N+1
  float* h1     = (float*)(row_ptr + (N + 1));       // N*HIDC
  float* h2     = h1 + (size_t)N * HIDC;             // N*HIDC
  float* psum   = h2 + (size_t)N * HIDC;             // B*16
  float* pcnt   = psum + (size_t)B * 16;             // B

  zero2_kernel<<<128, 256, 0, stream>>>(deg, N, (int*)psum, B * 16 + B);
  hist_kernel<<<(E + 255) / 256, 256, 0, stream>>>(edst, deg, pos, E);
  scan_kernel<<<1, 1024, 0, stream>>>((const int4*)deg, row_ptr, N);
  permute_kernel<<<(E + 255) / 256, 256, 0, stream>>>(
      edst, esrc, et, (const float2*)ef, row_ptr, pos, edges, E);

  const int g256 = (N + 15) / 16;     // 16 nodes per 256-thread block
  layer_kernel<IN1, HIDC, false, 256><<<g256, 256, 0, stream>>>(
      x, edges, row_ptr, emb1, wh1, bh1, wg1, bg1, root1, bias1,
      h1, nullptr, nullptr, nullptr, N, B);
  layer_kernel<HIDC, HIDC, false, 256><<<g256, 256, 0, stream>>>(
      h1, edges, row_ptr, emb2, wh2, bh2, wg2, bg2, root2, bias2,
      h2, nullptr, nullptr, nullptr, N, B);

  const int g1024 = (N + 63) / 64;    // 64 nodes per 1024-thread block
  layer_kernel<HIDC, OUT3, true, 1024><<<g1024, 1024, 0, stream>>>(
      h2, edges, row_ptr, emb3, wh3, bh3, wg3, bg3, root3, bias3,
      psum, ctype, bids, pcnt, N, B);

  finalize_kernel<<<1, 256, 0, stream>>>(psum, pcnt, (float*)d_out, B);
}